// Round 5
// baseline (217.520 us; speedup 1.0000x reference)
//
#include <hip/hip_runtime.h>
#include <stdint.h>

// Problem constants
#define SEQ   2048
#define EMB   1024
#define PROJ  1024
#define HEADS 16
#define HD    64
#define BATCH 2
#define MROWS (BATCH * SEQ)   // 4096
#define QKVN  3072            // fused QKV output width

typedef __attribute__((ext_vector_type(8))) __bf16 bf16x8;
typedef __attribute__((ext_vector_type(4))) __bf16 bf16x4;
typedef __attribute__((ext_vector_type(4))) float  f32x4;

static __device__ __forceinline__ __bf16 f2b(float f) {
  union { float f; uint32_t u; } a; a.f = f;
  uint32_t r = a.u + 0x7FFFu + ((a.u >> 16) & 1u);
  union { uint16_t u; __bf16 b; } o; o.u = (uint16_t)(r >> 16);
  return o.b;
}

#define GLOAD_LDS16(gsrc, ldst)                                                \
  __builtin_amdgcn_global_load_lds(                                            \
      (const __attribute__((address_space(1))) void*)(gsrc),                   \
      (__attribute__((address_space(3))) void*)(ldst), 16, 0, 0)

// ---------------------------------------------------------------------------
// fp32 -> bf16 elementwise cast (vectorized 4/thread)
// ---------------------------------------------------------------------------
__global__ void cast_f32_bf16(const float* __restrict__ in,
                              __bf16* __restrict__ out, int n) {
  int i = (blockIdx.x * blockDim.x + threadIdx.x) * 4;
  if (i + 3 < n) {
    float4 v = *reinterpret_cast<const float4*>(in + i);
    bf16x4 o;
    o[0] = f2b(v.x); o[1] = f2b(v.y); o[2] = f2b(v.z); o[3] = f2b(v.w);
    *reinterpret_cast<bf16x4*>(out + i) = o;
  }
}

// ---------------------------------------------------------------------------
// Transpose + cast the 4 weight matrices. z=0..2 -> rows z*1024.. of WqkvT,
// z=3 -> WoT. T[n][k] = (bf16) W[k][n].
// ---------------------------------------------------------------------------
__global__ void transpose_cast(const float* __restrict__ W0, const float* __restrict__ W1,
                               const float* __restrict__ W2, const float* __restrict__ W3,
                               __bf16* __restrict__ Tqkv, __bf16* __restrict__ To) {
  const float* W; __bf16* T;
  switch (blockIdx.z) {
    case 0: W = W0; T = Tqkv;                       break;
    case 1: W = W1; T = Tqkv + (size_t)1024 * 1024; break;
    case 2: W = W2; T = Tqkv + (size_t)2048 * 1024; break;
    default: W = W3; T = To;                        break;
  }
  __shared__ float tile[32][33];
  int k0 = blockIdx.x * 32, n0 = blockIdx.y * 32;
  int tx = threadIdx.x & 31, ty = threadIdx.x >> 5;  // 256 thr: ty 0..7
#pragma unroll
  for (int r = ty; r < 32; r += 8)
    tile[r][tx] = W[(size_t)(k0 + r) * 1024 + n0 + tx];
  __syncthreads();
#pragma unroll
  for (int r = ty; r < 32; r += 8)
    T[(size_t)(n0 + r) * 1024 + k0 + tx] = f2b(tile[tx][r]);
}

// ---------------------------------------------------------------------------
// bf16 GEMM, C = A[M,K] * Bt^T (Bt[N][K]). Tile BM x 128, BK=32.
// 256 thr = 4 waves in 2x2; wave tile (BM/2) x 64. MFMA 16x16x32.
// SCALE_Q: multiply output by 0.125 when col < 1024 (attention Q pre-scale).
// ---------------------------------------------------------------------------
template <int BM, bool OUT_BF16, bool SCALE_Q>
__global__ __launch_bounds__(256) void gemm_bt(const __bf16* __restrict__ A,
                                               const __bf16* __restrict__ Bt,
                                               void* __restrict__ Cout,
                                               int M, int N, int K) {
  constexpr int MI = BM / 32;  // m-frags per wave
  __shared__ __align__(16) __bf16 As[BM * 32];
  __shared__ __align__(16) __bf16 Bs[128 * 32];
  const int t = threadIdx.x;
  const int lane = t & 63, w = t >> 6;
  const int g = lane >> 4, l15 = lane & 15;
  const int m0 = blockIdx.x * BM, n0 = blockIdx.y * 128;
  const int wr = w >> 1, wc = w & 1;

  f32x4 acc[MI][4];
#pragma unroll
  for (int i = 0; i < MI; i++)
#pragma unroll
    for (int j = 0; j < 4; j++) acc[i][j] = {0.f, 0.f, 0.f, 0.f};

  for (int k0 = 0; k0 < K; k0 += 32) {
    __syncthreads();
#pragma unroll
    for (int c = t; c < BM * 4; c += 256)  // A tile [BM][32]
      GLOAD_LDS16(A + (size_t)(m0 + (c >> 2)) * K + k0 + (c & 3) * 8, As + c * 8);
#pragma unroll
    for (int c = t; c < 512; c += 256)     // Bt tile [128][32]
      GLOAD_LDS16(Bt + (size_t)(n0 + (c >> 2)) * K + k0 + (c & 3) * 8, Bs + c * 8);
    __syncthreads();

    bf16x8 af[MI], bfr[4];
#pragma unroll
    for (int mi = 0; mi < MI; mi++)
      af[mi] = *reinterpret_cast<const bf16x8*>(As + (wr * (BM / 2) + mi * 16 + l15) * 32 + g * 8);
#pragma unroll
    for (int ni = 0; ni < 4; ni++)
      bfr[ni] = *reinterpret_cast<const bf16x8*>(Bs + (wc * 64 + ni * 16 + l15) * 32 + g * 8);
#pragma unroll
    for (int mi = 0; mi < MI; mi++)
#pragma unroll
      for (int ni = 0; ni < 4; ni++)
        acc[mi][ni] = __builtin_amdgcn_mfma_f32_16x16x32_bf16(af[mi], bfr[ni], acc[mi][ni], 0, 0, 0);
  }

#pragma unroll
  for (int mi = 0; mi < MI; mi++)
#pragma unroll
    for (int ni = 0; ni < 4; ni++) {
      int row = m0 + wr * (BM / 2) + mi * 16 + g * 4;
      int col = n0 + wc * 64 + ni * 16 + l15;
#pragma unroll
      for (int r = 0; r < 4; r++) {
        float v = acc[mi][ni][r];
        if (SCALE_Q && col < 1024) v *= 0.125f;
        if (OUT_BF16)
          ((__bf16*)Cout)[(size_t)(row + r) * N + col] = f2b(v);
        else
          ((float*)Cout)[(size_t)(row + r) * N + col] = v;
      }
    }
}

// ---------------------------------------------------------------------------
// V pre-transpose: Vt[(bh*64 + d)*2048 + s] = QKV[b][s][2048 + h*64 + d].
// ---------------------------------------------------------------------------
__global__ void v_transpose(const __bf16* __restrict__ QKV, __bf16* __restrict__ Vt) {
  const int sb = blockIdx.x, bh = blockIdx.y;
  const int lane = threadIdx.x & 63, w = threadIdx.x >> 6;
  const int b = bh >> 4, h = bh & 15;
  const int s = sb * 64 + lane;
  const __bf16* src = QKV + (size_t)b * SEQ * QKVN + (size_t)s * QKVN + 2048 + h * 64 + w * 16;
  bf16x8 v0 = *reinterpret_cast<const bf16x8*>(src);
  bf16x8 v1 = *reinterpret_cast<const bf16x8*>(src + 8);
  __bf16* dst = Vt + ((size_t)bh * 64 + w * 16) * 2048 + s;
#pragma unroll
  for (int j = 0; j < 8; j++) dst[(size_t)j * 2048] = v0[j];
#pragma unroll
  for (int j = 0; j < 8; j++) dst[(size_t)(8 + j) * 2048] = v1[j];
}

// ---------------------------------------------------------------------------
// Causal flash attention, split-KV per chunk, XCD-localized.
// Grid 512 blocks x 512 thr (8 waves); 2 blocks/CU, 16 waves/CU.
// id: xcd = id&7 owns 4 heads; within = id>>3: bh = xcd*4+(within&3),
// pg = within>>2 (0..15). Wave w: pairIdx = pg*2 + ((w>>1)&1);
// chunk c = (w&1) ? 63-pairIdx : pairIdx; half = w>>2.
// Chunk c = 32 q-rows at qw=c*32, T = c/2+1 KV tiles; half 0 does tiles
// [0, ceil(T/2)), half 1 does [ceil(T/2), T). Max 16 serial units per wave
// (was 32/34) -- the measured wall is 2.2us per serial KV-unit per wave.
// Waves w and w+4 (same SIMD) hold the two halves; flash-combine via LDS.
// Swapped QK^T (D[kv][q], lane-local softmax state). Q pre-scaled by 1/8.
// ---------------------------------------------------------------------------
__global__ __launch_bounds__(512, 4) void attn_fwd(const __bf16* __restrict__ QKV,
                                                   const __bf16* __restrict__ Vt,
                                                   __bf16* __restrict__ ctx) {
  const int id = blockIdx.x;
  const int within = id >> 3;
  const int bh = (id & 7) * 4 + (within & 3);
  const int pg = within >> 2;                    // 0..15
  const int b = bh >> 4, h = bh & 15;
  const int t = threadIdx.x, lane = t & 63, w = t >> 6;
  const int g = lane >> 4, l15 = lane & 15;
  const int pairIdx = pg * 2 + ((w >> 1) & 1);   // 0..31
  const int c = (w & 1) ? (63 - pairIdx) : pairIdx;  // chunk 0..63
  const int half = w >> 2;                       // 0 or 1
  const int qw = c * 32;
  const int T = c / 2 + 1;
  const int tmid = (T + 1) >> 1;
  const int t0 = half ? tmid : 0;
  const int t1 = half ? T : tmid;

  __shared__ __align__(16) __bf16 P_lds[8][32][72];  // P staging; merge alias
  __shared__ float mlbuf[8][32][2];

  const __bf16* Qg  = QKV + (size_t)b * SEQ * QKVN + h * 64;
  const __bf16* Kg  = QKV + (size_t)b * SEQ * QKVN + 1024 + h * 64;
  const __bf16* VtH = Vt + (size_t)bh * 64 * 2048;

  f32x4 acco[2][4];
  float mrun[2] = {-1e30f, -1e30f};
  float lrun[2] = {0.f, 0.f};
#pragma unroll
  for (int m = 0; m < 2; m++)
#pragma unroll
    for (int nd = 0; nd < 4; nd++) acco[m][nd] = {0.f, 0.f, 0.f, 0.f};

  if (t0 < t1) {
    // Q fragments: qf[m][ks][j] = Q[qw+m*16+l15][ks*32+g*8+j]
    bf16x8 qf[2][2];
#pragma unroll
    for (int m = 0; m < 2; m++)
#pragma unroll
      for (int ks = 0; ks < 2; ks++)
        qf[m][ks] = *reinterpret_cast<const bf16x8*>(
            Qg + (size_t)(qw + m * 16 + l15) * QKVN + ks * 32 + g * 8);

    // preload K fragments for first tile
    bf16x8 kf[4][2], kn[4][2];
#pragma unroll
    for (int nb = 0; nb < 4; nb++) {
      const __bf16* kr = Kg + (size_t)(t0 * 64 + nb * 16 + l15) * QKVN + g * 8;
      kf[nb][0] = *reinterpret_cast<const bf16x8*>(kr);
      kf[nb][1] = *reinterpret_cast<const bf16x8*>(kr + 32);
    }

    for (int it = t0; it < t1; ++it) {
      const int kv0 = it * 64;
      const bool diag = (it == T - 1);

      // V fragments for current tile
      bf16x8 vb[4][2];
#pragma unroll
      for (int nd = 0; nd < 4; nd++)
#pragma unroll
        for (int ks = 0; ks < 2; ks++)
          vb[nd][ks] = *reinterpret_cast<const bf16x8*>(
              VtH + (size_t)(nd * 16 + l15) * 2048 + kv0 + ks * 32 + g * 8);

      // prefetch next tile's K fragments
      if (it + 1 < t1) {
#pragma unroll
        for (int nb = 0; nb < 4; nb++) {
          const __bf16* kr = Kg + (size_t)(kv0 + 64 + nb * 16 + l15) * QKVN + g * 8;
          kn[nb][0] = *reinterpret_cast<const bf16x8*>(kr);
          kn[nb][1] = *reinterpret_cast<const bf16x8*>(kr + 32);
        }
      }

      // ---- QK^T (swapped): accS[nb][m], D[kv][q]
      f32x4 accS[4][2];
#pragma unroll
      for (int nb = 0; nb < 4; nb++)
#pragma unroll
        for (int m = 0; m < 2; m++) accS[nb][m] = {0.f, 0.f, 0.f, 0.f};
#pragma unroll
      for (int nb = 0; nb < 4; nb++)
#pragma unroll
        for (int m = 0; m < 2; m++) {
          accS[nb][m] = __builtin_amdgcn_mfma_f32_16x16x32_bf16(kf[nb][0], qf[m][0], accS[nb][m], 0, 0, 0);
          accS[nb][m] = __builtin_amdgcn_mfma_f32_16x16x32_bf16(kf[nb][1], qf[m][1], accS[nb][m], 0, 0, 0);
        }

      // ---- causal mask (diagonal tile only)
      if (diag) {
#pragma unroll
        for (int nb = 0; nb < 4; nb++)
#pragma unroll
          for (int m = 0; m < 2; m++)
#pragma unroll
            for (int r = 0; r < 4; r++) {
              int kvi = kv0 + nb * 16 + g * 4 + r;
              int qi = qw + m * 16 + l15;
              if (kvi > qi) accS[nb][m][r] = -1e30f;
            }
      }

      // ---- online softmax (row = lane's own q = m*16+l15), defer-max THR=8
#pragma unroll
      for (int m = 0; m < 2; m++) {
        float pmax = -1e30f;
#pragma unroll
        for (int nb = 0; nb < 4; nb++)
#pragma unroll
          for (int r = 0; r < 4; r++) pmax = fmaxf(pmax, accS[nb][m][r]);
        pmax = fmaxf(pmax, __shfl_xor(pmax, 16));
        pmax = fmaxf(pmax, __shfl_xor(pmax, 32));
        if (!__all(pmax <= mrun[m] + 8.0f)) {
          float mnew = fmaxf(mrun[m], pmax);
          float corr = __expf(mrun[m] - mnew);
          mrun[m] = mnew;
          lrun[m] *= corr;
#pragma unroll
          for (int r = 0; r < 4; r++) {
            float cr = __shfl(corr, (g << 4) + (g << 2) + r);
#pragma unroll
            for (int nd = 0; nd < 4; nd++) acco[m][nd][r] *= cr;
          }
        }
        float lsum = 0.f;
#pragma unroll
        for (int nb = 0; nb < 4; nb++) {
          bf16x4 pk;
#pragma unroll
          for (int r = 0; r < 4; r++) {
            float pv = __expf(accS[nb][m][r] - mrun[m]);
            lsum += pv;
            pk[r] = (__bf16)pv;
          }
          *reinterpret_cast<bf16x4*>(&P_lds[w][m * 16 + l15][nb * 16 + g * 4]) = pk;
        }
        lsum += __shfl_xor(lsum, 16);
        lsum += __shfl_xor(lsum, 32);
        lrun[m] += lsum;
      }

      // ---- PV: O[q][d] += P[q][kv] * V[kv][d]
#pragma unroll
      for (int m = 0; m < 2; m++) {
        bf16x8 pa0 = *reinterpret_cast<const bf16x8*>(&P_lds[w][m * 16 + l15][g * 8]);
        bf16x8 pa1 = *reinterpret_cast<const bf16x8*>(&P_lds[w][m * 16 + l15][32 + g * 8]);
#pragma unroll
        for (int nd = 0; nd < 4; nd++) {
          acco[m][nd] = __builtin_amdgcn_mfma_f32_16x16x32_bf16(pa0, vb[nd][0], acco[m][nd], 0, 0, 0);
          acco[m][nd] = __builtin_amdgcn_mfma_f32_16x16x32_bf16(pa1, vb[nd][1], acco[m][nd], 0, 0, 0);
        }
      }

      if (it + 1 < t1) {
#pragma unroll
        for (int nb = 0; nb < 4; nb++) {
          kf[nb][0] = kn[nb][0];
          kf[nb][1] = kn[nb][1];
        }
      }
    }
  }

  // ---------------- merge: half1 stores normalized partial, half0 combines
  __syncthreads();  // KV loops done; P_lds dead -> reuse as fp16 partials
  _Float16* Pp = (_Float16*)P_lds;

  if (half) {
#pragma unroll
    for (int m = 0; m < 2; m++) {
      float inv = lrun[m] > 0.f ? 1.0f / lrun[m] : 0.f;
      if (g == 0) { mlbuf[w][m * 16 + l15][0] = mrun[m]; mlbuf[w][m * 16 + l15][1] = lrun[m]; }
#pragma unroll
      for (int r = 0; r < 4; r++) {
        float ir = __shfl(inv, (g << 4) + (g << 2) + r);
#pragma unroll
        for (int nd = 0; nd < 4; nd++)
          Pp[((size_t)w * 32 + m * 16 + g * 4 + r) * 72 + nd * 16 + l15] =
              (_Float16)(acco[m][nd][r] * ir);
      }
    }
  }
  __syncthreads();

  if (!half) {
    __bf16* Cg = ctx + (size_t)b * SEQ * 1024 + h * 64;
    const int pw = w + 4;
#pragma unroll
    for (int m = 0; m < 2; m++) {
      float m1 = mrun[m], l1 = lrun[m];
      float m2 = mlbuf[pw][m * 16 + l15][0];
      float l2 = mlbuf[pw][m * 16 + l15][1];
      float mx = fmaxf(m1, m2);
      float a1 = l1 * __expf(m1 - mx);
      float a2 = l2 * __expf(m2 - mx);
      float Li = 1.0f / (a1 + a2);
      float inv1 = l1 > 0.f ? 1.0f / l1 : 0.f;
      float s1 = a1 * inv1 * Li;
      float s2 = a2 * Li;
#pragma unroll
      for (int r = 0; r < 4; r++) {
        float w1 = __shfl(s1, (g << 4) + (g << 2) + r);
        float w2 = __shfl(s2, (g << 4) + (g << 2) + r);
        int qrow = qw + m * 16 + g * 4 + r;
#pragma unroll
        for (int nd = 0; nd < 4; nd++) {
          float o2 = (float)Pp[((size_t)pw * 32 + m * 16 + g * 4 + r) * 72 + nd * 16 + l15];
          Cg[(size_t)qrow * 1024 + nd * 16 + l15] = (__bf16)(acco[m][nd][r] * w1 + o2 * w2);
        }
      }
    }
  }
}

// ---------------------------------------------------------------------------
extern "C" void kernel_launch(void* const* d_in, const int* in_sizes, int n_in,
                              void* d_out, int out_size, void* d_ws, size_t ws_size,
                              hipStream_t stream) {
  const float* X  = (const float*)d_in[0];
  const float* Wq = (const float*)d_in[1];
  const float* Wk = (const float*)d_in[2];
  const float* Wv = (const float*)d_in[3];
  const float* Wo = (const float*)d_in[4];
  float* out = (float*)d_out;

  uint8_t* ws = (uint8_t*)d_ws;
  size_t off = 0;
  const size_t actBytes = (size_t)MROWS * 1024 * 2;          // 8 MB
  __bf16* Xb    = (__bf16*)(ws + off); off += actBytes;      // freed after QKV gemm
  __bf16* WqkvT = (__bf16*)(ws + off); off += (size_t)QKVN * 1024 * 2;
  __bf16* WoT   = (__bf16*)(ws + off); off += (size_t)1024 * 1024 * 2;
  __bf16* QKV   = (__bf16*)(ws + off); off += (size_t)MROWS * QKVN * 2;
  __bf16* Vt    = (__bf16*)(ws + off); off += actBytes;
  __bf16* Cb    = Xb;  // alias: X dead after QKV projection

  // 1) casts
  cast_f32_bf16<<<dim3(MROWS * 1024 / 4 / 256), dim3(256), 0, stream>>>(X, Xb, MROWS * 1024);
  transpose_cast<<<dim3(32, 32, 4), dim3(256), 0, stream>>>(Wq, Wk, Wv, Wo, WqkvT, WoT);

  // 2) fused QKV projection (Q pre-scaled by 1/8), 128x128 tiles
  gemm_bt<128, true, true><<<dim3(MROWS / 128, QKVN / 128), dim3(256), 0, stream>>>(
      Xb, WqkvT, QKV, MROWS, QKVN, EMB);

  // 3) V pre-transpose, then causal flash attention (split-KV, 4096 wave-jobs)
  v_transpose<<<dim3(SEQ / 64, BATCH * HEADS), dim3(256), 0, stream>>>(QKV, Vt);
  attn_fwd<<<dim3(512), dim3(512), 0, stream>>>(QKV, Vt, Cb);

  // 4) output projection (fp32 out), 64x128 tiles (512 blocks, 2/CU)
  gemm_bt<64, false, false><<<dim3(MROWS / 64, PROJ / 128), dim3(256), 0, stream>>>(
      Cb, WoT, out, MROWS, PROJ, PROJ);
}

// Round 6
// 143.195 us; speedup vs baseline: 1.5190x; 1.5190x over previous
//
#include <hip/hip_runtime.h>
#include <stdint.h>

// Problem constants
#define SEQ   2048
#define EMB   1024
#define PROJ  1024
#define HEADS 16
#define HD    64
#define BATCH 2
#define MROWS (BATCH * SEQ)   // 4096
#define QKVN  3072            // fused QKV output width

typedef __attribute__((ext_vector_type(8))) __bf16 bf16x8;
typedef __attribute__((ext_vector_type(4))) __bf16 bf16x4;
typedef __attribute__((ext_vector_type(4))) float  f32x4;

static __device__ __forceinline__ __bf16 f2b(float f) {
  union { float f; uint32_t u; } a; a.f = f;
  uint32_t r = a.u + 0x7FFFu + ((a.u >> 16) & 1u);
  union { uint16_t u; __bf16 b; } o; o.u = (uint16_t)(r >> 16);
  return o.b;
}

#define GLOAD_LDS16(gsrc, ldst)                                                \
  __builtin_amdgcn_global_load_lds(                                            \
      (const __attribute__((address_space(1))) void*)(gsrc),                   \
      (__attribute__((address_space(3))) void*)(ldst), 16, 0, 0)

// ---------------------------------------------------------------------------
// fp32 -> bf16 elementwise cast (vectorized 4/thread)
// ---------------------------------------------------------------------------
__global__ void cast_f32_bf16(const float* __restrict__ in,
                              __bf16* __restrict__ out, int n) {
  int i = (blockIdx.x * blockDim.x + threadIdx.x) * 4;
  if (i + 3 < n) {
    float4 v = *reinterpret_cast<const float4*>(in + i);
    bf16x4 o;
    o[0] = f2b(v.x); o[1] = f2b(v.y); o[2] = f2b(v.z); o[3] = f2b(v.w);
    *reinterpret_cast<bf16x4*>(out + i) = o;
  }
}

// ---------------------------------------------------------------------------
// Transpose + cast the 4 weight matrices. z=0..2 -> rows z*1024.. of WqkvT,
// z=3 -> WoT. T[n][k] = (bf16) W[k][n].
// ---------------------------------------------------------------------------
__global__ void transpose_cast(const float* __restrict__ W0, const float* __restrict__ W1,
                               const float* __restrict__ W2, const float* __restrict__ W3,
                               __bf16* __restrict__ Tqkv, __bf16* __restrict__ To) {
  const float* W; __bf16* T;
  switch (blockIdx.z) {
    case 0: W = W0; T = Tqkv;                       break;
    case 1: W = W1; T = Tqkv + (size_t)1024 * 1024; break;
    case 2: W = W2; T = Tqkv + (size_t)2048 * 1024; break;
    default: W = W3; T = To;                        break;
  }
  __shared__ float tile[32][33];
  int k0 = blockIdx.x * 32, n0 = blockIdx.y * 32;
  int tx = threadIdx.x & 31, ty = threadIdx.x >> 5;  // 256 thr: ty 0..7
#pragma unroll
  for (int r = ty; r < 32; r += 8)
    tile[r][tx] = W[(size_t)(k0 + r) * 1024 + n0 + tx];
  __syncthreads();
#pragma unroll
  for (int r = ty; r < 32; r += 8)
    T[(size_t)(n0 + r) * 1024 + k0 + tx] = f2b(tile[tx][r]);
}

// ---------------------------------------------------------------------------
// bf16 GEMM, C = A[M,K] * Bt^T (Bt[N][K]). Tile BM x 128, BK=32.
// 256 thr = 4 waves in 2x2; wave tile (BM/2) x 64. MFMA 16x16x32.
// SCALE_Q: multiply output by 0.125 when col < 1024 (attention Q pre-scale).
// ---------------------------------------------------------------------------
template <int BM, bool OUT_BF16, bool SCALE_Q>
__global__ __launch_bounds__(256) void gemm_bt(const __bf16* __restrict__ A,
                                               const __bf16* __restrict__ Bt,
                                               void* __restrict__ Cout,
                                               int M, int N, int K) {
  constexpr int MI = BM / 32;  // m-frags per wave
  __shared__ __align__(16) __bf16 As[BM * 32];
  __shared__ __align__(16) __bf16 Bs[128 * 32];
  const int t = threadIdx.x;
  const int lane = t & 63, w = t >> 6;
  const int g = lane >> 4, l15 = lane & 15;
  const int m0 = blockIdx.x * BM, n0 = blockIdx.y * 128;
  const int wr = w >> 1, wc = w & 1;

  f32x4 acc[MI][4];
#pragma unroll
  for (int i = 0; i < MI; i++)
#pragma unroll
    for (int j = 0; j < 4; j++) acc[i][j] = {0.f, 0.f, 0.f, 0.f};

  for (int k0 = 0; k0 < K; k0 += 32) {
    __syncthreads();
#pragma unroll
    for (int c = t; c < BM * 4; c += 256)  // A tile [BM][32]
      GLOAD_LDS16(A + (size_t)(m0 + (c >> 2)) * K + k0 + (c & 3) * 8, As + c * 8);
#pragma unroll
    for (int c = t; c < 512; c += 256)     // Bt tile [128][32]
      GLOAD_LDS16(Bt + (size_t)(n0 + (c >> 2)) * K + k0 + (c & 3) * 8, Bs + c * 8);
    __syncthreads();

    bf16x8 af[MI], bfr[4];
#pragma unroll
    for (int mi = 0; mi < MI; mi++)
      af[mi] = *reinterpret_cast<const bf16x8*>(As + (wr * (BM / 2) + mi * 16 + l15) * 32 + g * 8);
#pragma unroll
    for (int ni = 0; ni < 4; ni++)
      bfr[ni] = *reinterpret_cast<const bf16x8*>(Bs + (wc * 64 + ni * 16 + l15) * 32 + g * 8);
#pragma unroll
    for (int mi = 0; mi < MI; mi++)
#pragma unroll
      for (int ni = 0; ni < 4; ni++)
        acc[mi][ni] = __builtin_amdgcn_mfma_f32_16x16x32_bf16(af[mi], bfr[ni], acc[mi][ni], 0, 0, 0);
  }

#pragma unroll
  for (int mi = 0; mi < MI; mi++)
#pragma unroll
    for (int ni = 0; ni < 4; ni++) {
      int row = m0 + wr * (BM / 2) + mi * 16 + g * 4;
      int col = n0 + wc * 64 + ni * 16 + l15;
#pragma unroll
      for (int r = 0; r < 4; r++) {
        float v = acc[mi][ni][r];
        if (SCALE_Q && col < 1024) v *= 0.125f;
        if (OUT_BF16)
          ((__bf16*)Cout)[(size_t)(row + r) * N + col] = f2b(v);
        else
          ((float*)Cout)[(size_t)(row + r) * N + col] = v;
      }
    }
}

// ---------------------------------------------------------------------------
// V pre-transpose: Vt[(bh*64 + d)*2048 + s] = QKV[b][s][2048 + h*64 + d].
// ---------------------------------------------------------------------------
__global__ void v_transpose(const __bf16* __restrict__ QKV, __bf16* __restrict__ Vt) {
  const int sb = blockIdx.x, bh = blockIdx.y;
  const int lane = threadIdx.x & 63, w = threadIdx.x >> 6;
  const int b = bh >> 4, h = bh & 15;
  const int s = sb * 64 + lane;
  const __bf16* src = QKV + (size_t)b * SEQ * QKVN + (size_t)s * QKVN + 2048 + h * 64 + w * 16;
  bf16x8 v0 = *reinterpret_cast<const bf16x8*>(src);
  bf16x8 v1 = *reinterpret_cast<const bf16x8*>(src + 8);
  __bf16* dst = Vt + ((size_t)bh * 64 + w * 16) * 2048 + s;
#pragma unroll
  for (int j = 0; j < 8; j++) dst[(size_t)j * 2048] = v0[j];
#pragma unroll
  for (int j = 0; j < 8; j++) dst[(size_t)(8 + j) * 2048] = v1[j];
}

// ---------------------------------------------------------------------------
// Causal flash attention, split-KV per chunk, XCD-localized.
// Grid 512 blocks x 512 thr (8 waves). NOTE: __launch_bounds__ min-waves must
// stay at 2 -- forcing 4 caps VGPR at 64 and spills all fragment state to
// scratch (round-5 regression: WRITE_SIZE 15->317MB, 2x slower). At
// (512,2) the kernel uses ~112 VGPR -> HW 128 quantum -> 4 waves/SIMD anyway.
// id: xcd = id&7 owns 4 heads; within = id>>3: bh = xcd*4+(within&3),
// pg = within>>2 (0..15). Wave w: pairIdx = pg*2 + ((w>>1)&1);
// chunk c = (w&1) ? 63-pairIdx : pairIdx; half = w>>2.
// Chunk c = 32 q-rows at qw=c*32, T = c/2+1 KV tiles; half 0 does tiles
// [0, ceil(T/2)), half 1 does [ceil(T/2), T). Max 16 serial units per wave.
// Waves w and w+4 (same SIMD) hold the two halves; flash-combine via LDS.
// Swapped QK^T (D[kv][q], lane-local softmax state). Q pre-scaled by 1/8.
// ---------------------------------------------------------------------------
__global__ __launch_bounds__(512, 2) void attn_fwd(const __bf16* __restrict__ QKV,
                                                   const __bf16* __restrict__ Vt,
                                                   __bf16* __restrict__ ctx) {
  const int id = blockIdx.x;
  const int within = id >> 3;
  const int bh = (id & 7) * 4 + (within & 3);
  const int pg = within >> 2;                    // 0..15
  const int b = bh >> 4, h = bh & 15;
  const int t = threadIdx.x, lane = t & 63, w = t >> 6;
  const int g = lane >> 4, l15 = lane & 15;
  const int pairIdx = pg * 2 + ((w >> 1) & 1);   // 0..31
  const int c = (w & 1) ? (63 - pairIdx) : pairIdx;  // chunk 0..63
  const int half = w >> 2;                       // 0 or 1
  const int qw = c * 32;
  const int T = c / 2 + 1;
  const int tmid = (T + 1) >> 1;
  const int t0 = half ? tmid : 0;
  const int t1 = half ? T : tmid;

  __shared__ __align__(16) __bf16 P_lds[8][32][72];  // P staging; merge alias
  __shared__ float mlbuf[8][32][2];

  const __bf16* Qg  = QKV + (size_t)b * SEQ * QKVN + h * 64;
  const __bf16* Kg  = QKV + (size_t)b * SEQ * QKVN + 1024 + h * 64;
  const __bf16* VtH = Vt + (size_t)bh * 64 * 2048;

  f32x4 acco[2][4];
  float mrun[2] = {-1e30f, -1e30f};
  float lrun[2] = {0.f, 0.f};
#pragma unroll
  for (int m = 0; m < 2; m++)
#pragma unroll
    for (int nd = 0; nd < 4; nd++) acco[m][nd] = {0.f, 0.f, 0.f, 0.f};

  if (t0 < t1) {
    // Q fragments: qf[m][ks][j] = Q[qw+m*16+l15][ks*32+g*8+j]
    bf16x8 qf[2][2];
#pragma unroll
    for (int m = 0; m < 2; m++)
#pragma unroll
      for (int ks = 0; ks < 2; ks++)
        qf[m][ks] = *reinterpret_cast<const bf16x8*>(
            Qg + (size_t)(qw + m * 16 + l15) * QKVN + ks * 32 + g * 8);

    // preload K fragments for first tile
    bf16x8 kf[4][2], kn[4][2];
#pragma unroll
    for (int nb = 0; nb < 4; nb++) {
      const __bf16* kr = Kg + (size_t)(t0 * 64 + nb * 16 + l15) * QKVN + g * 8;
      kf[nb][0] = *reinterpret_cast<const bf16x8*>(kr);
      kf[nb][1] = *reinterpret_cast<const bf16x8*>(kr + 32);
    }

    for (int it = t0; it < t1; ++it) {
      const int kv0 = it * 64;
      const bool diag = (it == T - 1);

      // V fragments for current tile
      bf16x8 vb[4][2];
#pragma unroll
      for (int nd = 0; nd < 4; nd++)
#pragma unroll
        for (int ks = 0; ks < 2; ks++)
          vb[nd][ks] = *reinterpret_cast<const bf16x8*>(
              VtH + (size_t)(nd * 16 + l15) * 2048 + kv0 + ks * 32 + g * 8);

      // prefetch next tile's K fragments
      if (it + 1 < t1) {
#pragma unroll
        for (int nb = 0; nb < 4; nb++) {
          const __bf16* kr = Kg + (size_t)(kv0 + 64 + nb * 16 + l15) * QKVN + g * 8;
          kn[nb][0] = *reinterpret_cast<const bf16x8*>(kr);
          kn[nb][1] = *reinterpret_cast<const bf16x8*>(kr + 32);
        }
      }

      // ---- QK^T (swapped): accS[nb][m], D[kv][q]
      f32x4 accS[4][2];
#pragma unroll
      for (int nb = 0; nb < 4; nb++)
#pragma unroll
        for (int m = 0; m < 2; m++) accS[nb][m] = {0.f, 0.f, 0.f, 0.f};
#pragma unroll
      for (int nb = 0; nb < 4; nb++)
#pragma unroll
        for (int m = 0; m < 2; m++) {
          accS[nb][m] = __builtin_amdgcn_mfma_f32_16x16x32_bf16(kf[nb][0], qf[m][0], accS[nb][m], 0, 0, 0);
          accS[nb][m] = __builtin_amdgcn_mfma_f32_16x16x32_bf16(kf[nb][1], qf[m][1], accS[nb][m], 0, 0, 0);
        }

      // ---- causal mask (diagonal tile only)
      if (diag) {
#pragma unroll
        for (int nb = 0; nb < 4; nb++)
#pragma unroll
          for (int m = 0; m < 2; m++)
#pragma unroll
            for (int r = 0; r < 4; r++) {
              int kvi = kv0 + nb * 16 + g * 4 + r;
              int qi = qw + m * 16 + l15;
              if (kvi > qi) accS[nb][m][r] = -1e30f;
            }
      }

      // ---- online softmax (row = lane's own q = m*16+l15), defer-max THR=8
#pragma unroll
      for (int m = 0; m < 2; m++) {
        float pmax = -1e30f;
#pragma unroll
        for (int nb = 0; nb < 4; nb++)
#pragma unroll
          for (int r = 0; r < 4; r++) pmax = fmaxf(pmax, accS[nb][m][r]);
        pmax = fmaxf(pmax, __shfl_xor(pmax, 16));
        pmax = fmaxf(pmax, __shfl_xor(pmax, 32));
        if (!__all(pmax <= mrun[m] + 8.0f)) {
          float mnew = fmaxf(mrun[m], pmax);
          float corr = __expf(mrun[m] - mnew);
          mrun[m] = mnew;
          lrun[m] *= corr;
#pragma unroll
          for (int r = 0; r < 4; r++) {
            float cr = __shfl(corr, (g << 4) + (g << 2) + r);
#pragma unroll
            for (int nd = 0; nd < 4; nd++) acco[m][nd][r] *= cr;
          }
        }
        float lsum = 0.f;
#pragma unroll
        for (int nb = 0; nb < 4; nb++) {
          bf16x4 pk;
#pragma unroll
          for (int r = 0; r < 4; r++) {
            float pv = __expf(accS[nb][m][r] - mrun[m]);
            lsum += pv;
            pk[r] = (__bf16)pv;
          }
          *reinterpret_cast<bf16x4*>(&P_lds[w][m * 16 + l15][nb * 16 + g * 4]) = pk;
        }
        lsum += __shfl_xor(lsum, 16);
        lsum += __shfl_xor(lsum, 32);
        lrun[m] += lsum;
      }

      // ---- PV: O[q][d] += P[q][kv] * V[kv][d]
#pragma unroll
      for (int m = 0; m < 2; m++) {
        bf16x8 pa0 = *reinterpret_cast<const bf16x8*>(&P_lds[w][m * 16 + l15][g * 8]);
        bf16x8 pa1 = *reinterpret_cast<const bf16x8*>(&P_lds[w][m * 16 + l15][32 + g * 8]);
#pragma unroll
        for (int nd = 0; nd < 4; nd++) {
          acco[m][nd] = __builtin_amdgcn_mfma_f32_16x16x32_bf16(pa0, vb[nd][0], acco[m][nd], 0, 0, 0);
          acco[m][nd] = __builtin_amdgcn_mfma_f32_16x16x32_bf16(pa1, vb[nd][1], acco[m][nd], 0, 0, 0);
        }
      }

      if (it + 1 < t1) {
#pragma unroll
        for (int nb = 0; nb < 4; nb++) {
          kf[nb][0] = kn[nb][0];
          kf[nb][1] = kn[nb][1];
        }
      }
    }
  }

  // ---------------- merge: half1 stores normalized partial, half0 combines
  __syncthreads();  // KV loops done; P_lds dead -> reuse as fp16 partials
  _Float16* Pp = (_Float16*)P_lds;

  if (half) {
#pragma unroll
    for (int m = 0; m < 2; m++) {
      float inv = lrun[m] > 0.f ? 1.0f / lrun[m] : 0.f;
      if (g == 0) { mlbuf[w][m * 16 + l15][0] = mrun[m]; mlbuf[w][m * 16 + l15][1] = lrun[m]; }
#pragma unroll
      for (int r = 0; r < 4; r++) {
        float ir = __shfl(inv, (g << 4) + (g << 2) + r);
#pragma unroll
        for (int nd = 0; nd < 4; nd++)
          Pp[((size_t)w * 32 + m * 16 + g * 4 + r) * 72 + nd * 16 + l15] =
              (_Float16)(acco[m][nd][r] * ir);
      }
    }
  }
  __syncthreads();

  if (!half) {
    __bf16* Cg = ctx + (size_t)b * SEQ * 1024 + h * 64;
    const int pw = w + 4;
#pragma unroll
    for (int m = 0; m < 2; m++) {
      float m1 = mrun[m], l1 = lrun[m];
      float m2 = mlbuf[pw][m * 16 + l15][0];
      float l2 = mlbuf[pw][m * 16 + l15][1];
      float mx = fmaxf(m1, m2);
      float a1 = l1 * __expf(m1 - mx);
      float a2 = l2 * __expf(m2 - mx);
      float Li = 1.0f / (a1 + a2);
      float inv1 = l1 > 0.f ? 1.0f / l1 : 0.f;
      float s1 = a1 * inv1 * Li;
      float s2 = a2 * Li;
#pragma unroll
      for (int r = 0; r < 4; r++) {
        float w1 = __shfl(s1, (g << 4) + (g << 2) + r);
        float w2 = __shfl(s2, (g << 4) + (g << 2) + r);
        int qrow = qw + m * 16 + g * 4 + r;
#pragma unroll
        for (int nd = 0; nd < 4; nd++) {
          float o2 = (float)Pp[((size_t)pw * 32 + m * 16 + g * 4 + r) * 72 + nd * 16 + l15];
          Cg[(size_t)qrow * 1024 + nd * 16 + l15] = (__bf16)(acco[m][nd][r] * w1 + o2 * w2);
        }
      }
    }
  }
}

// ---------------------------------------------------------------------------
extern "C" void kernel_launch(void* const* d_in, const int* in_sizes, int n_in,
                              void* d_out, int out_size, void* d_ws, size_t ws_size,
                              hipStream_t stream) {
  const float* X  = (const float*)d_in[0];
  const float* Wq = (const float*)d_in[1];
  const float* Wk = (const float*)d_in[2];
  const float* Wv = (const float*)d_in[3];
  const float* Wo = (const float*)d_in[4];
  float* out = (float*)d_out;

  uint8_t* ws = (uint8_t*)d_ws;
  size_t off = 0;
  const size_t actBytes = (size_t)MROWS * 1024 * 2;          // 8 MB
  __bf16* Xb    = (__bf16*)(ws + off); off += actBytes;      // freed after QKV gemm
  __bf16* WqkvT = (__bf16*)(ws + off); off += (size_t)QKVN * 1024 * 2;
  __bf16* WoT   = (__bf16*)(ws + off); off += (size_t)1024 * 1024 * 2;
  __bf16* QKV   = (__bf16*)(ws + off); off += (size_t)MROWS * QKVN * 2;
  __bf16* Vt    = (__bf16*)(ws + off); off += actBytes;
  __bf16* Cb    = Xb;  // alias: X dead after QKV projection

  // 1) casts
  cast_f32_bf16<<<dim3(MROWS * 1024 / 4 / 256), dim3(256), 0, stream>>>(X, Xb, MROWS * 1024);
  transpose_cast<<<dim3(32, 32, 4), dim3(256), 0, stream>>>(Wq, Wk, Wv, Wo, WqkvT, WoT);

  // 2) fused QKV projection (Q pre-scaled by 1/8), 128x128 tiles
  gemm_bt<128, true, true><<<dim3(MROWS / 128, QKVN / 128), dim3(256), 0, stream>>>(
      Xb, WqkvT, QKV, MROWS, QKVN, EMB);

  // 3) V pre-transpose, then causal flash attention (split-KV, 4096 wave-jobs)
  v_transpose<<<dim3(SEQ / 64, BATCH * HEADS), dim3(256), 0, stream>>>(QKV, Vt);
  attn_fwd<<<dim3(512), dim3(512), 0, stream>>>(QKV, Vt, Cb);

  // 4) output projection (fp32 out), 64x128 tiles (512 blocks, 2/CU)
  gemm_bt<64, false, false><<<dim3(MROWS / 64, PROJ / 128), dim3(256), 0, stream>>>(
      Cb, WoT, out, MROWS, PROJ, PROJ);
}